// Round 1
// baseline (1114.158 us; speedup 1.0000x reference)
//
#include <hip/hip_runtime.h>
#include <math.h>

// Phase quantizer, v2 (STEPS=2), f32 in/out.
// Plan: 3 streaming kernels over w (recompute instead of materializing err1):
//   K1: partial sums for step-1 scales (no atan2 needed; mask == |y|<=|x|)
//   K2: recompute step1 elementwise -> err1, partial sums for step-2 scales
//   K3: recompute steps 1+2, write qw_real / qw_imag
// Scales passed via tiny ws accumulators (float atomics + exact uint counts).

#define NM_PI    3.14159265358979323846f
#define NM_PI_2  1.57079632679489661923f
#define NM_2PI   6.28318530717958647692f

__device__ __forceinline__ float wrap_pi(float d) {
  d = (d >  NM_PI) ? d - NM_2PI : d;
  d = (d < -NM_PI) ? d + NM_2PI : d;
  return d;
}

// Soft assignment directions: dre = p0 - p2, dim = p1 - p3 of
// softmax(-wrap(phase - centers)^2 / tau), centers = {0, pi/2, pi, -pi/2}.
__device__ __forceinline__ void soft_dirs(float phase, float inv_tau,
                                          float& dre, float& dim) {
  float d0 = phase;                      // already in (-pi, pi]
  float d1 = wrap_pi(phase - NM_PI_2);
  float d2 = wrap_pi(phase - NM_PI);
  float d3 = wrap_pi(phase + NM_PI_2);
  float l0 = -d0 * d0, l1 = -d1 * d1, l2 = -d2 * d2, l3 = -d3 * d3;
  float m = fmaxf(fmaxf(l0, l1), fmaxf(l2, l3));
  float e0 = __expf((l0 - m) * inv_tau);
  float e1 = __expf((l1 - m) * inv_tau);
  float e2 = __expf((l2 - m) * inv_tau);
  float e3 = __expf((l3 - m) * inv_tau);
  float inv_sum = 1.0f / (e0 + e1 + e2 + e3);
  dre = (e0 - e2) * inv_sum;
  dim = (e1 - e3) * inv_sum;
}

__device__ __forceinline__ float finalize_s(float sum, unsigned cnt) {
  float c = (float)(cnt > 0u ? cnt : 1u);
  float s = sum / c;
  s = (cnt > 0u) ? s : 0.0f;
  return fmaxf(s, 1e-6f);
}

// Block (256 threads = 4 waves) reduction of 2 floats + 1 uint, then atomics.
__device__ __forceinline__ void block_acc(float sre, float sim, unsigned cnt,
                                          float* accf, unsigned* accu) {
  #pragma unroll
  for (int o = 32; o > 0; o >>= 1) {
    sre += __shfl_down(sre, o);
    sim += __shfl_down(sim, o);
    cnt += __shfl_down(cnt, o);
  }
  __shared__ float rf0[4];
  __shared__ float rf1[4];
  __shared__ unsigned ru[4];
  int wave = threadIdx.x >> 6;
  int lane = threadIdx.x & 63;
  if (lane == 0) { rf0[wave] = sre; rf1[wave] = sim; ru[wave] = cnt; }
  __syncthreads();
  if (threadIdx.x == 0) {
    float a = rf0[0] + rf0[1] + rf0[2] + rf0[3];
    float b = rf1[0] + rf1[1] + rf1[2] + rf1[3];
    unsigned c = ru[0] + ru[1] + ru[2] + ru[3];
    atomicAdd(accf + 0, a);
    atomicAdd(accf + 1, b);
    atomicAdd(accu, c);
  }
}

__global__ __launch_bounds__(256) void pq_k1(const float4* __restrict__ wr,
                                             const float4* __restrict__ wi,
                                             int n4, float* accf, unsigned* accu) {
  float sre = 0.f, sim = 0.f;
  unsigned cnt = 0u;
  int stride = gridDim.x * blockDim.x;
  for (int i = blockIdx.x * blockDim.x + threadIdx.x; i < n4; i += stride) {
    float4 r = wr[i], g = wi[i];
    float xs[4] = {r.x, r.y, r.z, r.w};
    float ys[4] = {g.x, g.y, g.z, g.w};
    #pragma unroll
    for (int k = 0; k < 4; ++k) {
      float ax = fabsf(xs[k]), ay = fabsf(ys[k]);
      bool is_re = (ay <= ax);          // == phase-based mask_real (interior)
      sre += is_re ? ax : 0.f;
      sim += is_re ? 0.f : ay;
      cnt += is_re ? 1u : 0u;
    }
  }
  block_acc(sre, sim, cnt, accf, accu);
}

__global__ __launch_bounds__(256) void pq_k2(const float4* __restrict__ wr,
                                             const float4* __restrict__ wi,
                                             int n4, unsigned nm,
                                             const float* __restrict__ temp,
                                             const float* __restrict__ accf1,
                                             const unsigned* __restrict__ accu1,
                                             float* accf2, unsigned* accu2) {
  unsigned c1 = accu1[0];
  float s_re = finalize_s(accf1[0], c1);
  float s_im = finalize_s(accf1[1], nm - c1);
  float inv_tau = 1.0f / (temp[0] + 1e-6f);
  float sre = 0.f, sim = 0.f;
  unsigned cnt = 0u;
  int stride = gridDim.x * blockDim.x;
  for (int i = blockIdx.x * blockDim.x + threadIdx.x; i < n4; i += stride) {
    float4 r = wr[i], g = wi[i];
    float xs[4] = {r.x, r.y, r.z, r.w};
    float ys[4] = {g.x, g.y, g.z, g.w};
    #pragma unroll
    for (int k = 0; k < 4; ++k) {
      float x = xs[k], y = ys[k];
      float phase = atan2f(y, x);
      float dre, dim;
      soft_dirs(phase, inv_tau, dre, dim);
      float er = x - dre * s_re;        // err1
      float ei = y - dim * s_im;
      float ax = fabsf(er), ay = fabsf(ei);
      bool is_re = (ay <= ax);
      sre += is_re ? ax : 0.f;
      sim += is_re ? 0.f : ay;
      cnt += is_re ? 1u : 0u;
    }
  }
  block_acc(sre, sim, cnt, accf2, accu2);
}

__global__ __launch_bounds__(256) void pq_k3(const float4* __restrict__ wr,
                                             const float4* __restrict__ wi,
                                             int n4, unsigned nm,
                                             const float* __restrict__ temp,
                                             const float* __restrict__ accf1,
                                             const unsigned* __restrict__ accu1,
                                             const float* __restrict__ accf2,
                                             const unsigned* __restrict__ accu2,
                                             float4* __restrict__ out) {
  unsigned c1 = accu1[0];
  float s_re1 = finalize_s(accf1[0], c1);
  float s_im1 = finalize_s(accf1[1], nm - c1);
  unsigned c2 = accu2[0];
  float s_re2 = finalize_s(accf2[0], c2);
  float s_im2 = finalize_s(accf2[1], nm - c2);
  float inv_tau = 1.0f / (temp[0] + 1e-6f);
  int stride = gridDim.x * blockDim.x;
  for (int i = blockIdx.x * blockDim.x + threadIdx.x; i < n4; i += stride) {
    float4 r = wr[i], g = wi[i];
    float xs[4] = {r.x, r.y, r.z, r.w};
    float ys[4] = {g.x, g.y, g.z, g.w};
    float qr[4], qi[4];
    #pragma unroll
    for (int k = 0; k < 4; ++k) {
      float x = xs[k], y = ys[k];
      // step 1
      float phase1 = atan2f(y, x);
      float d1re, d1im;
      soft_dirs(phase1, inv_tau, d1re, d1im);
      float q1r = d1re * s_re1;
      float q1i = d1im * s_im1;
      float er = x - q1r;
      float ei = y - q1i;
      // step 2
      float phase2 = atan2f(ei, er);
      float d2re, d2im;
      soft_dirs(phase2, inv_tau, d2re, d2im);
      qr[k] = q1r + d2re * s_re2;
      qi[k] = q1i + d2im * s_im2;
    }
    float4 o0 = {qr[0], qr[1], qr[2], qr[3]};
    float4 o1 = {qi[0], qi[1], qi[2], qi[3]};
    out[i] = o0;          // qw_real
    out[n4 + i] = o1;     // qw_imag
  }
}

extern "C" void kernel_launch(void* const* d_in, const int* in_sizes, int n_in,
                              void* d_out, int out_size, void* d_ws, size_t ws_size,
                              hipStream_t stream) {
  const float4* wr = (const float4*)d_in[0];
  const float4* wi = (const float4*)d_in[1];
  const float* temp = (const float*)d_in[2];
  int nm = in_sizes[0];
  int n4 = nm / 4;

  // ws layout (4-byte words): [0]=sum_re1 [1]=sum_im1 [2]=cnt1 [3]=pad
  //                           [4]=sum_re2 [5]=sum_im2 [6]=cnt2 [7]=pad
  float* accf = (float*)d_ws;
  unsigned* accu = (unsigned*)d_ws;
  hipMemsetAsync(d_ws, 0, 32, stream);

  dim3 block(256);
  dim3 grid(8192);
  pq_k1<<<grid, block, 0, stream>>>(wr, wi, n4, accf + 0, accu + 2);
  pq_k2<<<grid, block, 0, stream>>>(wr, wi, n4, (unsigned)nm, temp,
                                    accf + 0, accu + 2, accf + 4, accu + 6);
  pq_k3<<<grid, block, 0, stream>>>(wr, wi, n4, (unsigned)nm, temp,
                                    accf + 0, accu + 2, accf + 4, accu + 6,
                                    (float4*)d_out);
}

// Round 2
// 547.821 us; speedup vs baseline: 2.0338x; 2.0338x over previous
//
#include <hip/hip_runtime.h>
#include <math.h>

// Phase quantizer, v2 (STEPS=2), f32 in/out.
// R1: (a) no atomics — per-block partials to private ws slots + tiny reduce
//     kernels (R0's 8192-deep same-address atomic chains cost ~325us/kernel);
//     (b) closed-form softmax: weights {1, c1*P, c1/P, c2*P^2}, P=exp(pi*u/tau),
//     u=atan(min/max) — one poly-atan + one __expf instead of atan2f + 4 expf.

#define NM_PI     3.14159265358979323846f
#define NM_PI2_4  2.46740110027233965468f   // (pi/2)^2
#define NM_PISQ   9.86960440108935861883f   // pi^2

#define NBLK 4096

// atan(r) for r in [0,1], A&S 4.4.49, |err| <= 1e-5 rad.
__device__ __forceinline__ float atan_poly(float r) {
  float r2 = r * r;
  float p = fmaf(-0.0851330f, r2, 0.1801410f);
  p = fmaf(p, r2, -0.3302995f);
  p = fmaf(0.0208351f, r2 * r2, p);          // a9*r^4 folded in
  // recompute cleanly in Horner order:
  float q = 0.0208351f;
  q = fmaf(q, r2, -0.0851330f);
  q = fmaf(q, r2, 0.1801410f);
  q = fmaf(q, r2, -0.3302995f);
  q = fmaf(q, r2, 0.9998660f);
  (void)p;
  return r * q;
}

// Soft assignment directions (softmax over 4 phase centers), branchless.
// k_t = pi/tau, c1 = exp(-(pi/2)^2/tau), c2 = exp(-pi^2/tau).
__device__ __forceinline__ void soft_dirs(float x, float y, float k_t,
                                          float c1, float c2,
                                          float& dre, float& dim) {
  float ax = fabsf(x), ay = fabsf(y);
  float hi = fmaxf(ax, ay), lo = fminf(ax, ay);
  float r = lo * __builtin_amdgcn_rcpf(fmaxf(hi, 1e-30f));
  float u = atan_poly(r);                    // angle from dominant axis
  float P = __expf(k_t * u);
  float Pi = __builtin_amdgcn_rcpf(P);
  float wo = c2 * P * P;                     // opposite axis
  float wp = c1 * P;                         // near perpendicular (minor sign)
  float wq = c1 * Pi;                        // far perpendicular
  float inv_sum = __builtin_amdgcn_rcpf(1.0f + wo + wp + wq);
  float dmaj = (1.0f - wo) * inv_sum;
  float dmin = (wp - wq) * inv_sum;
  bool xdom = (ax >= ay);
  float sx = copysignf(1.0f, x), sy = copysignf(1.0f, y);
  dre = sx * (xdom ? dmaj : dmin);
  dim = sy * (xdom ? dmin : dmaj);
}

__device__ __forceinline__ float finalize_s(float sum, unsigned cnt) {
  float c = (float)(cnt > 0u ? cnt : 1u);
  float s = sum * __builtin_amdgcn_rcpf(c);
  s = (cnt > 0u) ? s : 0.0f;
  return fmaxf(s, 1e-6f);
}

// In-block reduction (up to 16 waves). Result valid in thread 0.
__device__ __forceinline__ void block_reduce3(float& sre, float& sim,
                                              unsigned& cnt) {
  #pragma unroll
  for (int o = 32; o > 0; o >>= 1) {
    sre += __shfl_down(sre, o);
    sim += __shfl_down(sim, o);
    cnt += __shfl_down(cnt, o);
  }
  __shared__ float rf0[16];
  __shared__ float rf1[16];
  __shared__ unsigned ru[16];
  int wave = threadIdx.x >> 6;
  int lane = threadIdx.x & 63;
  int nw = blockDim.x >> 6;
  if (lane == 0) { rf0[wave] = sre; rf1[wave] = sim; ru[wave] = cnt; }
  __syncthreads();
  if (threadIdx.x == 0) {
    float a = rf0[0], b = rf1[0];
    unsigned c = ru[0];
    for (int w = 1; w < nw; ++w) { a += rf0[w]; b += rf1[w]; c += ru[w]; }
    sre = a; sim = b; cnt = c;
  }
}

// K1: step-1 scale partials. mask_real == (|y| <= |x|); no transcendentals.
__global__ __launch_bounds__(256) void pq_k1(const float4* __restrict__ wr,
                                             const float4* __restrict__ wi,
                                             int n4, float* __restrict__ psre,
                                             float* __restrict__ psim,
                                             unsigned* __restrict__ pcnt) {
  float sre = 0.f, sim = 0.f;
  unsigned cnt = 0u;
  int stride = gridDim.x * blockDim.x;
  for (int i = blockIdx.x * blockDim.x + threadIdx.x; i < n4; i += stride) {
    float4 r = wr[i], g = wi[i];
    float xs[4] = {r.x, r.y, r.z, r.w};
    float ys[4] = {g.x, g.y, g.z, g.w};
    #pragma unroll
    for (int k = 0; k < 4; ++k) {
      float ax = fabsf(xs[k]), ay = fabsf(ys[k]);
      bool is_re = (ay <= ax);
      sre += is_re ? ax : 0.f;
      sim += is_re ? 0.f : ay;
      cnt += is_re ? 1u : 0u;
    }
  }
  block_reduce3(sre, sim, cnt);
  if (threadIdx.x == 0) {
    psre[blockIdx.x] = sre;
    psim[blockIdx.x] = sim;
    pcnt[blockIdx.x] = cnt;
  }
}

// Reduce NBLK partials -> finalized scales finals[0]=s_re, finals[1]=s_im.
__global__ __launch_bounds__(1024) void pq_reduce(const float* __restrict__ psre,
                                                  const float* __restrict__ psim,
                                                  const unsigned* __restrict__ pcnt,
                                                  unsigned nm,
                                                  float* __restrict__ finals) {
  float sre = 0.f, sim = 0.f;
  unsigned cnt = 0u;
  for (int i = threadIdx.x; i < NBLK; i += 1024) {
    sre += psre[i];
    sim += psim[i];
    cnt += pcnt[i];
  }
  block_reduce3(sre, sim, cnt);
  if (threadIdx.x == 0) {
    finals[0] = finalize_s(sre, cnt);
    finals[1] = finalize_s(sim, nm - cnt);
  }
}

// K2: recompute step 1, accumulate step-2 scale partials.
__global__ __launch_bounds__(256) void pq_k2(const float4* __restrict__ wr,
                                             const float4* __restrict__ wi,
                                             int n4,
                                             const float* __restrict__ temp,
                                             const float* __restrict__ finals1,
                                             float* __restrict__ psre,
                                             float* __restrict__ psim,
                                             unsigned* __restrict__ pcnt) {
  float s_re = finals1[0], s_im = finals1[1];
  float it = __builtin_amdgcn_rcpf(temp[0] + 1e-6f);
  float k_t = NM_PI * it;
  float c1 = __expf(-NM_PI2_4 * it);
  float c2 = __expf(-NM_PISQ * it);
  float sre = 0.f, sim = 0.f;
  unsigned cnt = 0u;
  int stride = gridDim.x * blockDim.x;
  for (int i = blockIdx.x * blockDim.x + threadIdx.x; i < n4; i += stride) {
    float4 r = wr[i], g = wi[i];
    float xs[4] = {r.x, r.y, r.z, r.w};
    float ys[4] = {g.x, g.y, g.z, g.w};
    #pragma unroll
    for (int k = 0; k < 4; ++k) {
      float x = xs[k], y = ys[k];
      float dre, dim;
      soft_dirs(x, y, k_t, c1, c2, dre, dim);
      float er = x - dre * s_re;
      float ei = y - dim * s_im;
      float ax = fabsf(er), ay = fabsf(ei);
      bool is_re = (ay <= ax);
      sre += is_re ? ax : 0.f;
      sim += is_re ? 0.f : ay;
      cnt += is_re ? 1u : 0u;
    }
  }
  block_reduce3(sre, sim, cnt);
  if (threadIdx.x == 0) {
    psre[blockIdx.x] = sre;
    psim[blockIdx.x] = sim;
    pcnt[blockIdx.x] = cnt;
  }
}

// K3: recompute steps 1+2, write qw_real / qw_imag.
__global__ __launch_bounds__(256) void pq_k3(const float4* __restrict__ wr,
                                             const float4* __restrict__ wi,
                                             int n4,
                                             const float* __restrict__ temp,
                                             const float* __restrict__ finals1,
                                             const float* __restrict__ finals2,
                                             float4* __restrict__ out) {
  float s_re1 = finals1[0], s_im1 = finals1[1];
  float s_re2 = finals2[0], s_im2 = finals2[1];
  float it = __builtin_amdgcn_rcpf(temp[0] + 1e-6f);
  float k_t = NM_PI * it;
  float c1 = __expf(-NM_PI2_4 * it);
  float c2 = __expf(-NM_PISQ * it);
  int stride = gridDim.x * blockDim.x;
  for (int i = blockIdx.x * blockDim.x + threadIdx.x; i < n4; i += stride) {
    float4 r = wr[i], g = wi[i];
    float xs[4] = {r.x, r.y, r.z, r.w};
    float ys[4] = {g.x, g.y, g.z, g.w};
    float qr[4], qi[4];
    #pragma unroll
    for (int k = 0; k < 4; ++k) {
      float x = xs[k], y = ys[k];
      float d1re, d1im;
      soft_dirs(x, y, k_t, c1, c2, d1re, d1im);
      float q1r = d1re * s_re1;
      float q1i = d1im * s_im1;
      float er = x - q1r;
      float ei = y - q1i;
      float d2re, d2im;
      soft_dirs(er, ei, k_t, c1, c2, d2re, d2im);
      qr[k] = fmaf(d2re, s_re2, q1r);
      qi[k] = fmaf(d2im, s_im2, q1i);
    }
    float4 o0 = {qr[0], qr[1], qr[2], qr[3]};
    float4 o1 = {qi[0], qi[1], qi[2], qi[3]};
    out[i] = o0;
    out[n4 + i] = o1;
  }
}

extern "C" void kernel_launch(void* const* d_in, const int* in_sizes, int n_in,
                              void* d_out, int out_size, void* d_ws, size_t ws_size,
                              hipStream_t stream) {
  const float4* wr = (const float4*)d_in[0];
  const float4* wi = (const float4*)d_in[1];
  const float* temp = (const float*)d_in[2];
  int nm = in_sizes[0];
  int n4 = nm / 4;

  // ws layout (4B words):
  //   [0..7]                 finals: 0=s_re1 1=s_im1 2=s_re2 3=s_im2
  //   [8        .. 8+NB)     p1_sre
  //   [8+NB     .. 8+2NB)    p1_sim
  //   [8+2NB    .. 8+3NB)    p1_cnt (uint)
  //   [8+3NB    .. 8+6NB)    pass-2 partials, same order
  float* w32 = (float*)d_ws;
  unsigned* u32 = (unsigned*)d_ws;
  float* finals1 = w32 + 0;
  float* finals2 = w32 + 2;
  float* p1_sre = w32 + 8;
  float* p1_sim = p1_sre + NBLK;
  unsigned* p1_cnt = u32 + 8 + 2 * NBLK;
  float* p2_sre = w32 + 8 + 3 * NBLK;
  float* p2_sim = p2_sre + NBLK;
  unsigned* p2_cnt = u32 + 8 + 5 * NBLK;

  dim3 block(256);
  dim3 grid(NBLK);
  pq_k1<<<grid, block, 0, stream>>>(wr, wi, n4, p1_sre, p1_sim, p1_cnt);
  pq_reduce<<<1, 1024, 0, stream>>>(p1_sre, p1_sim, p1_cnt, (unsigned)nm, finals1);
  pq_k2<<<grid, block, 0, stream>>>(wr, wi, n4, temp, finals1,
                                    p2_sre, p2_sim, p2_cnt);
  pq_reduce<<<1, 1024, 0, stream>>>(p2_sre, p2_sim, p2_cnt, (unsigned)nm, finals2);
  pq_k3<<<grid, block, 0, stream>>>(wr, wi, n4, temp, finals1, finals2,
                                    (float4*)d_out);
}